// Round 1
// 217.347 us; speedup vs baseline: 1.0990x; 1.0990x over previous
//
#include <hip/hip_runtime.h>

// ---------------------------------------------------------------------------
// MQA: out = softmax((X Wq)(X Wk)^T / 32)(X Wv) Wo, MQA broadcast K/V.
// B=2, S=2048, IN=HID=1024, H=16, D=64.
// Round 9: VALU-trim of mqa_flash_mfma (was VALUBusy 65% / MfmaUtil 16%):
//   - softmax scale C2=log2e/32 folded into Q-projection epilogue (oscale),
//     so attention does exp2(sa) directly (-16 mul/chunk/wave)
//   - P packing via v_cvt_pk_bf16_f32 (2 f32 -> 1 packed bf16 reg, HW RNE)
//     instead of manual RNE bit-ops (-~48 VALU ops/chunk/wave)
//   - persistent zero16 acc: sa = mfma(kf0,qf0,zero16) kills the 16
//     v_mov zero-init per chunk
//   - __builtin_amdgcn_exp2f for a bare v_exp_f32
//   - proj's fp32->bf16 A-conversion also moved to cvt_pk (48 -> 8 ops/k-step)
// Round 8 structure (S^T trick, 32x32x16 MFMA) unchanged otherwise.
// ---------------------------------------------------------------------------

typedef unsigned int   u32;
typedef unsigned short u16;
typedef union { float4 v; float f[4]; } f4u;
typedef __attribute__((ext_vector_type(8)))  short frag16;  // 8 bf16 (4 VGPR)
typedef __attribute__((ext_vector_type(4)))  float f32x4;
typedef __attribute__((ext_vector_type(16))) float f32x16;  // 32x32 MFMA acc
typedef union { frag16 v; u32 w[4]; u16 e[8]; } bf8u;

static __device__ __forceinline__ u16 f2bf(float x) {
  union { float f; u32 u; } v; v.f = x;
  u32 r = v.u + 0x7fff + ((v.u >> 16) & 1);   // RNE
  return (u16)(r >> 16);
}

// HW packed f32x2 -> bf16x2 convert (RNE). No builtin on gfx950 (m240) —
// inline asm, same pattern as learn_hip m214v22 (refcheck'd there).
static __device__ __forceinline__ u32 cvt_pk_bf16(float lo, float hi) {
  u32 r;
  asm("v_cvt_pk_bf16_f32 %0, %1, %2" : "=v"(r) : "v"(lo), "v"(hi));
  return r;
}

// ---------------------------------------------------------------------------
// 64x64 transpose+convert tile (prep_w helper).
// ---------------------------------------------------------------------------
static __device__ void tcvt_tile(const float* __restrict__ src,
                                 u16* __restrict__ dst,
                                 int C, int ldT, int rt, int ct,
                                 float (*t)[65]) {
  const int r0 = rt * 64, c0 = ct * 64;
  const int tr  = threadIdx.x >> 4;
  const int tc4 = (threadIdx.x & 15) * 4;
#pragma unroll
  for (int i = 0; i < 4; ++i) {
    f4u v; v.v = *(const float4*)(src + (size_t)(r0 + tr + i * 16) * C + c0 + tc4);
    t[tr + i * 16][tc4 + 0] = v.f[0];
    t[tr + i * 16][tc4 + 1] = v.f[1];
    t[tr + i * 16][tc4 + 2] = v.f[2];
    t[tr + i * 16][tc4 + 3] = v.f[3];
  }
  __syncthreads();
#pragma unroll
  for (int i = 0; i < 4; ++i) {
    const int oc = tr + i * 16;
    ushort4 o;
    o.x = f2bf(t[tc4 + 0][oc]);
    o.y = f2bf(t[tc4 + 1][oc]);
    o.z = f2bf(t[tc4 + 2][oc]);
    o.w = f2bf(t[tc4 + 3][oc]);
    *(ushort4*)(dst + (size_t)(c0 + oc) * ldT + r0 + tc4) = o;
  }
}

__global__ __launch_bounds__(256)
void prep_w(const float* __restrict__ Wq, const float* __restrict__ Wo,
            const float* __restrict__ Wk, const float* __restrict__ Wv,
            u16* __restrict__ wq_t, u16* __restrict__ wo_t,
            u16* __restrict__ wk_t, u16* __restrict__ wv_t) {
  __shared__ float t[64][65];
  const int bid = blockIdx.x;
  if (bid < 256)      tcvt_tile(Wq, wq_t, 1024, 1024, bid >> 4, bid & 15, t);
  else if (bid < 512) tcvt_tile(Wo, wo_t, 1024, 1024, (bid - 256) >> 4, (bid - 256) & 15, t);
  else if (bid < 528) tcvt_tile(Wk, wk_t, 64, 1024, bid - 512, 0, t);
  else                tcvt_tile(Wv, wv_t, 64, 1024, bid - 528, 0, t);
}

// ---------------------------------------------------------------------------
// 64x64-tile bf16 MFMA GEMM device fn. Round 9: oscale on the epilogue
// (softmax scale folding for Q-proj), cvt_pk in the fp32->bf16 A path.
// ---------------------------------------------------------------------------
#define GP 72
template <bool A_FP32>
static __device__ void gemm64(const float* __restrict__ Af32,
                              const u16* __restrict__ Abf,
                              const u16* __restrict__ Bt,
                              const float* __restrict__ bias,
                              void* __restrict__ Cout, int out_mode,
                              float oscale,
                              int row0, int col0, int N, int K, int ldT,
                              u16* As, u16* Bs) {
  const int tid  = threadIdx.x;
  const int lane = tid & 63;
  const int quad = lane >> 4, l15 = lane & 15;
  const int w = tid >> 6, wy = w >> 1, wx = w & 1;

  f32x4 acc[2][2];
#pragma unroll
  for (int i = 0; i < 2; ++i)
#pragma unroll
    for (int j = 0; j < 2; ++j) {
      acc[i][j][0] = 0.f; acc[i][j][1] = 0.f;
      acc[i][j][2] = 0.f; acc[i][j][3] = 0.f;
    }

  const int r = tid >> 2, c16 = (tid & 3) * 16;

  for (int k0 = 0; k0 < K; k0 += 64) {
    frag16 a0, a1;
    if (A_FP32) {
      const float* ap = Af32 + (size_t)(row0 + r) * K + k0 + c16;
      f4u x0, x1, x2, x3;
      x0.v = *(const float4*)(ap);
      x1.v = *(const float4*)(ap + 4);
      x2.v = *(const float4*)(ap + 8);
      x3.v = *(const float4*)(ap + 12);
      bf8u t0, t1;
      t0.w[0] = cvt_pk_bf16(x0.f[0], x0.f[1]);
      t0.w[1] = cvt_pk_bf16(x0.f[2], x0.f[3]);
      t0.w[2] = cvt_pk_bf16(x1.f[0], x1.f[1]);
      t0.w[3] = cvt_pk_bf16(x1.f[2], x1.f[3]);
      t1.w[0] = cvt_pk_bf16(x2.f[0], x2.f[1]);
      t1.w[1] = cvt_pk_bf16(x2.f[2], x2.f[3]);
      t1.w[2] = cvt_pk_bf16(x3.f[0], x3.f[1]);
      t1.w[3] = cvt_pk_bf16(x3.f[2], x3.f[3]);
      a0 = t0.v; a1 = t1.v;
    } else {
      const u16* ap = Abf + (size_t)(row0 + r) * K + k0 + c16;
      a0 = *(const frag16*)(ap);
      a1 = *(const frag16*)(ap + 8);
    }
    const u16* bp = Bt + (size_t)(col0 + r) * K + k0 + c16;
    const frag16 b0 = *(const frag16*)(bp);
    const frag16 b1 = *(const frag16*)(bp + 8);
    __syncthreads();
    *(frag16*)(&As[r * GP + c16])     = a0;
    *(frag16*)(&As[r * GP + c16 + 8]) = a1;
    *(frag16*)(&Bs[r * GP + c16])     = b0;
    *(frag16*)(&Bs[r * GP + c16 + 8]) = b1;
    __syncthreads();
#pragma unroll
    for (int ks = 0; ks < 2; ++ks) {
      frag16 af[2], bf[2];
#pragma unroll
      for (int i = 0; i < 2; ++i)
        af[i] = *(const frag16*)(&As[(wy * 32 + i * 16 + l15) * GP + ks * 32 + quad * 8]);
#pragma unroll
      for (int j = 0; j < 2; ++j)
        bf[j] = *(const frag16*)(&Bs[(wx * 32 + j * 16 + l15) * GP + ks * 32 + quad * 8]);
#pragma unroll
      for (int i = 0; i < 2; ++i)
#pragma unroll
        for (int j = 0; j < 2; ++j)
          acc[i][j] = __builtin_amdgcn_mfma_f32_16x16x32_bf16(af[i], bf[j], acc[i][j], 0, 0, 0);
    }
  }

  float bj[2];
#pragma unroll
  for (int j = 0; j < 2; ++j)
    bj[j] = bias[col0 + wx * 32 + j * 16 + l15];

#pragma unroll
  for (int i = 0; i < 2; ++i) {
#pragma unroll
    for (int rr = 0; rr < 4; ++rr) {
      const size_t row = row0 + wy * 32 + i * 16 + quad * 4 + rr;
#pragma unroll
      for (int j = 0; j < 2; ++j) {
        const float v = (acc[i][j][rr] + bj[j]) * oscale;
        const int col = col0 + wx * 32 + j * 16 + l15;
        if (out_mode == 0)      ((float*)Cout)[row * N + col] = v;
        else if (out_mode == 1) ((u16*)Cout)[row * N + col] = f2bf(v);
        else                    ((u16*)Cout)[(size_t)col * ldT + row] = f2bf(v);
      }
    }
  }
}

#define C2_SCALE 0.045084220027780106f   // log2(e)/32, folded into Q-proj

__global__ __launch_bounds__(256, 4)
void proj(const float* __restrict__ query, const float* __restrict__ key,
          const float* __restrict__ value,
          const u16* __restrict__ wq_t, const u16* __restrict__ wk_t,
          const u16* __restrict__ wv_t,
          const float* __restrict__ bq, const float* __restrict__ bk,
          const float* __restrict__ bv,
          u16* __restrict__ q_bf, u16* __restrict__ k_bf,
          u16* __restrict__ vt_bf, int M, int K) {
  __shared__ __align__(16) u16 As[64 * GP];
  __shared__ __align__(16) u16 Bs[64 * GP];
  const int bid = blockIdx.x;
  if (bid < 64)
    gemm64<true>(key, nullptr, wk_t, bk, k_bf, 1, 1.0f, bid * 64, 0, 64, K, 0, As, Bs);
  else if (bid < 128)
    gemm64<true>(value, nullptr, wv_t, bv, vt_bf, 2, 1.0f, (bid - 64) * 64, 0, 64, K, M, As, Bs);
  else {
    const int q = bid - 128;
    gemm64<true>(query, nullptr, wq_t, bq, q_bf, 1, C2_SCALE,
                 (q >> 4) * 64, (q & 15) * 64, 1024, K, 0, As, Bs);
  }
}

__global__ __launch_bounds__(256, 4)
void out_proj(const u16* __restrict__ ao, const u16* __restrict__ wo_t,
              const float* __restrict__ bo, float* __restrict__ out,
              int M, int K) {
  __shared__ __align__(16) u16 As[64 * GP];
  __shared__ __align__(16) u16 Bs[64 * GP];
  gemm64<false>(nullptr, ao, wo_t, bo, out, 0, 1.0f,
                blockIdx.y * 64, blockIdx.x * 64, 1024, K, 0, As, Bs);
}

// ---------------------------------------------------------------------------
// Flash MQA attention: mfma_f32_32x32x16_bf16, S^T trick.
// grid (S/64, H, B), block 256 = 4 waves. Wave w: scores role (kh=w&1 key-
// half, qh=w>>1 q-half); PV role (qh, dh=w&1).
// 32x32x16 layouts: A[m=l&31][k=8*(l>>5)+j]; B[k=8*(l>>5)+j][n=l&31];
//                   C: col=l&31, row=(reg&3)+8*(reg>>2)+4*(l>>5).
// Per chunk: stage K[key][d],Vt[d][key] -> S^T=K.Q^T (4 MFMA; B=Q in regs,
// C-init from persistent zero16) -> p=exp2(s) (scale pre-folded into Q)
// -> P to Ps[q][key] via 2x v_cvt_pk_bf16_f32 + b64 store -> sync ->
// PV: A=Ps b128, B=Vt b128, 4 MFMA -> O in C layout [q][d].
// ---------------------------------------------------------------------------
#define APITCH 72

__global__ __launch_bounds__(256)
void mqa_flash_mfma(const u16* __restrict__ Qb,  // [B,S,1024] bf16 (pre-scaled by C2)
                    const u16* __restrict__ Kb,  // [B,S,64]   bf16
                    const u16* __restrict__ Vt,  // [64][B*S]  bf16 (transposed)
                    u16* __restrict__ O) {       // [B,S,1024] bf16
  const int S = 2048, HID = 1024, D = 64, BS = 4096;
  __shared__ u16 Ks[64 * APITCH];   // K[key][d]
  __shared__ u16 Vs[64 * APITCH];   // V^T[d][key]
  __shared__ u16 Ps[64 * APITCH];   // P[q][key]
  __shared__ float red[2][64];      // per-key-half l partials

  const int tid  = threadIdx.x;
  const int lane = tid & 63;
  const int w    = tid >> 6;
  const int l31  = lane & 31;
  const int hh   = lane >> 5;        // lane half (0/1)
  const int kh   = w & 1;            // key-half for scores / d-half for PV
  const int qh   = w >> 1;           // q-half
  const int qb = blockIdx.x, h = blockIdx.y, b = blockIdx.z;

  // Q B-fragments, register-resident: B[k=d][n=q], lane: q=qh*32+l31,
  // d = ks*16 + 8*hh + j  -> Qb[row][h*64 + ...] b128 loads.
  const u16* qrow = Qb + (size_t)(b * S + qb * 64 + qh * 32 + l31) * HID + h * D;
  frag16 qf[4];
#pragma unroll
  for (int ks = 0; ks < 4; ++ks)
    qf[ks] = *(const frag16*)(qrow + ks * 16 + hh * 8);

  // Persistent zero accumulator: feeds the first score-MFMA's C operand so
  // sa needs no per-chunk v_mov zero-init (16 VGPR, well under budget).
  f32x16 zero16;
#pragma unroll
  for (int r = 0; r < 16; ++r) zero16[r] = 0.f;

  f32x16 o_acc;
#pragma unroll
  for (int r = 0; r < 16; ++r) o_acc[r] = 0.f;
  float l_lane = 0.f;

  for (int kc = 0; kc < S; kc += 64) {
    __syncthreads();  // PV (prev chunk) done with Ks/Vs/Ps
    {
      const u16* ksrc = Kb + (size_t)(b * S + kc) * D;
      const u16* vsrc = Vt + (size_t)(b * S + kc);
#pragma unroll
      for (int i = 0; i < 2; ++i) {
        const int c = tid + i * 256;
        const int r = c >> 3, col = (c & 7) * 8;
        *(frag16*)(&Ks[r * APITCH + col]) = *(const frag16*)(ksrc + r * D + col);
        *(frag16*)(&Vs[r * APITCH + col]) = *(const frag16*)(vsrc + (size_t)r * BS + col);
      }
    }
    __syncthreads();

    // ---- S^T = K . Q^T : A[m=key]=Ks rows, B=Q regs; first MFMA C=zero16 ----
    f32x16 sa;
#pragma unroll
    for (int ks = 0; ks < 4; ++ks) {
      const frag16 kf = *(const frag16*)(&Ks[(kh * 32 + l31) * APITCH + ks * 16 + hh * 8]);
      sa = __builtin_amdgcn_mfma_f32_32x32x16_bf16(kf, qf[ks], ks ? sa : zero16, 0, 0, 0);
    }

    // ---- p = exp2(s) (scale pre-folded); lane's 16 vals: q = qh*32+l31,
    //      key = kh*32 + (r&3) + 8*(r>>2) + 4*hh  -> 4 runs of 4 ----
    const int qrow_l = qh * 32 + l31;
    u16* prow = &Ps[qrow_l * APITCH + kh * 32];
#pragma unroll
    for (int g = 0; g < 4; ++g) {
      const float p0 = __builtin_amdgcn_exp2f(sa[g * 4 + 0]);
      const float p1 = __builtin_amdgcn_exp2f(sa[g * 4 + 1]);
      const float p2 = __builtin_amdgcn_exp2f(sa[g * 4 + 2]);
      const float p3 = __builtin_amdgcn_exp2f(sa[g * 4 + 3]);
      l_lane += (p0 + p1) + (p2 + p3);
      uint2 pk;
      pk.x = cvt_pk_bf16(p0, p1);
      pk.y = cvt_pk_bf16(p2, p3);
      *(uint2*)(&prow[g * 8 + hh * 4]) = pk;
    }
    __syncthreads();  // P complete across waves

    // ---- PV: O[q][d] += P[q][k] V[k][d]; A=Ps[q][key] b128, B=Vt[d][key] b128
#pragma unroll
    for (int ks = 0; ks < 4; ++ks) {
      const frag16 pf = *(const frag16*)(&Ps[(qh * 32 + l31) * APITCH + ks * 16 + hh * 8]);
      const frag16 vf = *(const frag16*)(&Vs[(kh * 32 + l31) * APITCH + ks * 16 + hh * 8]);
      o_acc = __builtin_amdgcn_mfma_f32_32x32x16_bf16(pf, vf, o_acc, 0, 0, 0);
    }
  }

  // ---- l reduction: lane+lane^32 (same q, complementary keys), then
  //      across the two key-half waves via LDS ----
  l_lane += __shfl_xor(l_lane, 32);
  __syncthreads();
  if (lane < 32) red[kh][qh * 32 + l31] = l_lane;
  __syncthreads();

  // ---- epilogue: O C-layout col=d=l31(+kh*32), row q per reg pattern ----
#pragma unroll
  for (int r = 0; r < 16; ++r) {
    const int q_local = qh * 32 + (r & 3) + 8 * (r >> 2) + 4 * hh;
    const float li = 1.f / (red[0][q_local] + red[1][q_local]);
    u16* orow = O + (size_t)(b * S + qb * 64 + q_local) * HID + h * D;
    orow[kh * 32 + l31] = f2bf(o_acc[r] * li);
  }
}

extern "C" void kernel_launch(void* const* d_in, const int* in_sizes, int n_in,
                              void* d_out, int out_size, void* d_ws, size_t ws_size,
                              hipStream_t stream) {
  const float* query = (const float*)d_in[0];
  const float* key   = (const float*)d_in[1];
  const float* value = (const float*)d_in[2];
  const float* Wq    = (const float*)d_in[3];
  const float* bq    = (const float*)d_in[4];
  const float* Wk    = (const float*)d_in[5];
  const float* bk    = (const float*)d_in[6];
  const float* Wv    = (const float*)d_in[7];
  const float* bv    = (const float*)d_in[8];
  const float* Wo    = (const float*)d_in[9];
  const float* bo    = (const float*)d_in[10];
  float* out = (float*)d_out;

  const int B = 2, S = 2048, IN = 1024, HID = 1024, H = 16, D = 64;
  const int M = B * S;  // 4096
  const size_t MB = 1024 * 1024;

  char* ws = (char*)d_ws;
  u16* q_bf  = (u16*)ws;                           // [0, 8MB)
  u16* ao_bf = (u16*)(ws + 8 * MB);                // [8, 16MB)
  u16* k_bf  = (u16*)(ws + 16 * MB);               // 0.5 MB
  u16* vt_bf = (u16*)(ws + 16 * MB + 512 * 1024);  // 0.5 MB
  u16* wq_t  = (u16*)(ws + 17 * MB);               // 2 MB [1024][1024]
  u16* wo_t  = (u16*)(ws + 19 * MB);               // 2 MB [1024][1024]
  u16* wk_t  = (u16*)(ws + 21 * MB);               // 128 KB [64][1024]
  u16* wv_t  = (u16*)(ws + 21 * MB + 128 * 1024);  // 128 KB [64][1024]

  dim3 blk(256);
  prep_w<<<dim3(544), blk, 0, stream>>>(Wq, Wo, Wk, Wv, wq_t, wo_t, wk_t, wv_t);
  proj<<<dim3(1152), blk, 0, stream>>>(query, key, value, wq_t, wk_t, wv_t,
                                       bq, bk, bv, q_bf, k_bf, vt_bf, M, IN);
  mqa_flash_mfma<<<dim3(S / 64, H, B), blk, 0, stream>>>(q_bf, k_bf, vt_bf, ao_bf);
  out_proj<<<dim3(HID / 64, M / 64), blk, 0, stream>>>(ao_bf, wo_t, bo, out, M, HID);
}

// Round 2
// 216.511 us; speedup vs baseline: 1.1032x; 1.0039x over previous
//
#include <hip/hip_runtime.h>

// ---------------------------------------------------------------------------
// MQA: out = softmax((X Wq)(X Wk)^T / 32)(X Wv) Wo, MQA broadcast K/V.
// B=2, S=2048, IN=HID=1024, H=16, D=64.
// Round 10: mqa_flash_mfma pipeline restructure (was 44% stall: MfmaUtil 22 +
// VALUBusy 34, HBM 3%):
//   - T14 async-STAGE: next chunk's K/V global loads issued at top of the
//     iteration into registers, written to LDS only after PV -> ~200cyc L2
//     latency hidden under scores+softmax+PV.
//   - V fragments hoisted to regs (vf[4]) before the softmax barrier, so
//     after sync1 no wave reads Ks/Vs -> stage-write needs no WAR barrier.
//     Barriers per chunk: 3 -> 2, still single-buffered LDS (28 KB).
//   - __launch_bounds__(256,4) pins VGPR <= 128 (est. peak ~110) so
//     occupancy stays 16 waves/CU.
// Round 9 (scale folded into Q-proj, cvt_pk P-pack, zero16 acc) retained.
// prep_w / proj / out_proj unchanged.
// ---------------------------------------------------------------------------

typedef unsigned int   u32;
typedef unsigned short u16;
typedef union { float4 v; float f[4]; } f4u;
typedef __attribute__((ext_vector_type(8)))  short frag16;  // 8 bf16 (4 VGPR)
typedef __attribute__((ext_vector_type(4)))  float f32x4;
typedef __attribute__((ext_vector_type(16))) float f32x16;  // 32x32 MFMA acc
typedef union { frag16 v; u32 w[4]; u16 e[8]; } bf8u;

static __device__ __forceinline__ u16 f2bf(float x) {
  union { float f; u32 u; } v; v.f = x;
  u32 r = v.u + 0x7fff + ((v.u >> 16) & 1);   // RNE
  return (u16)(r >> 16);
}

// HW packed f32x2 -> bf16x2 convert (RNE). No builtin on gfx950 (m240) —
// inline asm, same pattern as learn_hip m214v22 (refcheck'd there).
static __device__ __forceinline__ u32 cvt_pk_bf16(float lo, float hi) {
  u32 r;
  asm("v_cvt_pk_bf16_f32 %0, %1, %2" : "=v"(r) : "v"(lo), "v"(hi));
  return r;
}

// ---------------------------------------------------------------------------
// 64x64 transpose+convert tile (prep_w helper).
// ---------------------------------------------------------------------------
static __device__ void tcvt_tile(const float* __restrict__ src,
                                 u16* __restrict__ dst,
                                 int C, int ldT, int rt, int ct,
                                 float (*t)[65]) {
  const int r0 = rt * 64, c0 = ct * 64;
  const int tr  = threadIdx.x >> 4;
  const int tc4 = (threadIdx.x & 15) * 4;
#pragma unroll
  for (int i = 0; i < 4; ++i) {
    f4u v; v.v = *(const float4*)(src + (size_t)(r0 + tr + i * 16) * C + c0 + tc4);
    t[tr + i * 16][tc4 + 0] = v.f[0];
    t[tr + i * 16][tc4 + 1] = v.f[1];
    t[tr + i * 16][tc4 + 2] = v.f[2];
    t[tr + i * 16][tc4 + 3] = v.f[3];
  }
  __syncthreads();
#pragma unroll
  for (int i = 0; i < 4; ++i) {
    const int oc = tr + i * 16;
    ushort4 o;
    o.x = f2bf(t[tc4 + 0][oc]);
    o.y = f2bf(t[tc4 + 1][oc]);
    o.z = f2bf(t[tc4 + 2][oc]);
    o.w = f2bf(t[tc4 + 3][oc]);
    *(ushort4*)(dst + (size_t)(c0 + oc) * ldT + r0 + tc4) = o;
  }
}

__global__ __launch_bounds__(256)
void prep_w(const float* __restrict__ Wq, const float* __restrict__ Wo,
            const float* __restrict__ Wk, const float* __restrict__ Wv,
            u16* __restrict__ wq_t, u16* __restrict__ wo_t,
            u16* __restrict__ wk_t, u16* __restrict__ wv_t) {
  __shared__ float t[64][65];
  const int bid = blockIdx.x;
  if (bid < 256)      tcvt_tile(Wq, wq_t, 1024, 1024, bid >> 4, bid & 15, t);
  else if (bid < 512) tcvt_tile(Wo, wo_t, 1024, 1024, (bid - 256) >> 4, (bid - 256) & 15, t);
  else if (bid < 528) tcvt_tile(Wk, wk_t, 64, 1024, bid - 512, 0, t);
  else                tcvt_tile(Wv, wv_t, 64, 1024, bid - 528, 0, t);
}

// ---------------------------------------------------------------------------
// 64x64-tile bf16 MFMA GEMM device fn (unchanged from Round 9).
// ---------------------------------------------------------------------------
#define GP 72
template <bool A_FP32>
static __device__ void gemm64(const float* __restrict__ Af32,
                              const u16* __restrict__ Abf,
                              const u16* __restrict__ Bt,
                              const float* __restrict__ bias,
                              void* __restrict__ Cout, int out_mode,
                              float oscale,
                              int row0, int col0, int N, int K, int ldT,
                              u16* As, u16* Bs) {
  const int tid  = threadIdx.x;
  const int lane = tid & 63;
  const int quad = lane >> 4, l15 = lane & 15;
  const int w = tid >> 6, wy = w >> 1, wx = w & 1;

  f32x4 acc[2][2];
#pragma unroll
  for (int i = 0; i < 2; ++i)
#pragma unroll
    for (int j = 0; j < 2; ++j) {
      acc[i][j][0] = 0.f; acc[i][j][1] = 0.f;
      acc[i][j][2] = 0.f; acc[i][j][3] = 0.f;
    }

  const int r = tid >> 2, c16 = (tid & 3) * 16;

  for (int k0 = 0; k0 < K; k0 += 64) {
    frag16 a0, a1;
    if (A_FP32) {
      const float* ap = Af32 + (size_t)(row0 + r) * K + k0 + c16;
      f4u x0, x1, x2, x3;
      x0.v = *(const float4*)(ap);
      x1.v = *(const float4*)(ap + 4);
      x2.v = *(const float4*)(ap + 8);
      x3.v = *(const float4*)(ap + 12);
      bf8u t0, t1;
      t0.w[0] = cvt_pk_bf16(x0.f[0], x0.f[1]);
      t0.w[1] = cvt_pk_bf16(x0.f[2], x0.f[3]);
      t0.w[2] = cvt_pk_bf16(x1.f[0], x1.f[1]);
      t0.w[3] = cvt_pk_bf16(x1.f[2], x1.f[3]);
      t1.w[0] = cvt_pk_bf16(x2.f[0], x2.f[1]);
      t1.w[1] = cvt_pk_bf16(x2.f[2], x2.f[3]);
      t1.w[2] = cvt_pk_bf16(x3.f[0], x3.f[1]);
      t1.w[3] = cvt_pk_bf16(x3.f[2], x3.f[3]);
      a0 = t0.v; a1 = t1.v;
    } else {
      const u16* ap = Abf + (size_t)(row0 + r) * K + k0 + c16;
      a0 = *(const frag16*)(ap);
      a1 = *(const frag16*)(ap + 8);
    }
    const u16* bp = Bt + (size_t)(col0 + r) * K + k0 + c16;
    const frag16 b0 = *(const frag16*)(bp);
    const frag16 b1 = *(const frag16*)(bp + 8);
    __syncthreads();
    *(frag16*)(&As[r * GP + c16])     = a0;
    *(frag16*)(&As[r * GP + c16 + 8]) = a1;
    *(frag16*)(&Bs[r * GP + c16])     = b0;
    *(frag16*)(&Bs[r * GP + c16 + 8]) = b1;
    __syncthreads();
#pragma unroll
    for (int ks = 0; ks < 2; ++ks) {
      frag16 af[2], bf[2];
#pragma unroll
      for (int i = 0; i < 2; ++i)
        af[i] = *(const frag16*)(&As[(wy * 32 + i * 16 + l15) * GP + ks * 32 + quad * 8]);
#pragma unroll
      for (int j = 0; j < 2; ++j)
        bf[j] = *(const frag16*)(&Bs[(wx * 32 + j * 16 + l15) * GP + ks * 32 + quad * 8]);
#pragma unroll
      for (int i = 0; i < 2; ++i)
#pragma unroll
        for (int j = 0; j < 2; ++j)
          acc[i][j] = __builtin_amdgcn_mfma_f32_16x16x32_bf16(af[i], bf[j], acc[i][j], 0, 0, 0);
    }
  }

  float bj[2];
#pragma unroll
  for (int j = 0; j < 2; ++j)
    bj[j] = bias[col0 + wx * 32 + j * 16 + l15];

#pragma unroll
  for (int i = 0; i < 2; ++i) {
#pragma unroll
    for (int rr = 0; rr < 4; ++rr) {
      const size_t row = row0 + wy * 32 + i * 16 + quad * 4 + rr;
#pragma unroll
      for (int j = 0; j < 2; ++j) {
        const float v = (acc[i][j][rr] + bj[j]) * oscale;
        const int col = col0 + wx * 32 + j * 16 + l15;
        if (out_mode == 0)      ((float*)Cout)[row * N + col] = v;
        else if (out_mode == 1) ((u16*)Cout)[row * N + col] = f2bf(v);
        else                    ((u16*)Cout)[(size_t)col * ldT + row] = f2bf(v);
      }
    }
  }
}

#define C2_SCALE 0.045084220027780106f   // log2(e)/32, folded into Q-proj

__global__ __launch_bounds__(256, 4)
void proj(const float* __restrict__ query, const float* __restrict__ key,
          const float* __restrict__ value,
          const u16* __restrict__ wq_t, const u16* __restrict__ wk_t,
          const u16* __restrict__ wv_t,
          const float* __restrict__ bq, const float* __restrict__ bk,
          const float* __restrict__ bv,
          u16* __restrict__ q_bf, u16* __restrict__ k_bf,
          u16* __restrict__ vt_bf, int M, int K) {
  __shared__ __align__(16) u16 As[64 * GP];
  __shared__ __align__(16) u16 Bs[64 * GP];
  const int bid = blockIdx.x;
  if (bid < 64)
    gemm64<true>(key, nullptr, wk_t, bk, k_bf, 1, 1.0f, bid * 64, 0, 64, K, 0, As, Bs);
  else if (bid < 128)
    gemm64<true>(value, nullptr, wv_t, bv, vt_bf, 2, 1.0f, (bid - 64) * 64, 0, 64, K, M, As, Bs);
  else {
    const int q = bid - 128;
    gemm64<true>(query, nullptr, wq_t, bq, q_bf, 1, C2_SCALE,
                 (q >> 4) * 64, (q & 15) * 64, 1024, K, 0, As, Bs);
  }
}

__global__ __launch_bounds__(256, 4)
void out_proj(const u16* __restrict__ ao, const u16* __restrict__ wo_t,
              const float* __restrict__ bo, float* __restrict__ out,
              int M, int K) {
  __shared__ __align__(16) u16 As[64 * GP];
  __shared__ __align__(16) u16 Bs[64 * GP];
  gemm64<false>(nullptr, ao, wo_t, bo, out, 0, 1.0f,
                blockIdx.y * 64, blockIdx.x * 64, 1024, K, 0, As, Bs);
}

// ---------------------------------------------------------------------------
// Flash MQA attention: mfma_f32_32x32x16_bf16, S^T trick, 2-barrier pipeline.
// grid (S/64, H, B), block 256 = 4 waves. Wave w: scores role (kh=w&1 key-
// half, qh=w>>1 q-half); PV role (qh, dh=w&1).
// 32x32x16 layouts: A[m=l&31][k=8*(l>>5)+j]; B[k=8*(l>>5)+j][n=l&31];
//                   C: col=l&31, row=(reg&3)+8*(reg>>2)+4*(l>>5).
// Per chunk t:
//   issue global loads of chunk t+1 -> regs (T14: latency hides under compute)
//   vf[4] <- Vs (hoisted V frags; after sync1 nobody reads Ks/Vs)
//   scores: 4 MFMA (A=Ks rows, B=Q regs, C-init zero16)
//   softmax: exp2 + cvt_pk -> Ps
//   sync1 (Ps RAW; all Ks/Vs reads complete)
//   PV: 4 MFMA (A=Ps b128, B=vf regs)
//   stage: prefetch regs -> Ks/Vs (no WAR barrier needed)
//   sync2 (KV RAW for t+1; Ps WAR)
// ---------------------------------------------------------------------------
#define APITCH 72

__global__ __launch_bounds__(256, 4)
void mqa_flash_mfma(const u16* __restrict__ Qb,  // [B,S,1024] bf16 (pre-scaled by C2)
                    const u16* __restrict__ Kb,  // [B,S,64]   bf16
                    const u16* __restrict__ Vt,  // [64][B*S]  bf16 (transposed)
                    u16* __restrict__ O) {       // [B,S,1024] bf16
  const int S = 2048, HID = 1024, D = 64, BS = 4096;
  __shared__ u16 Ks[64 * APITCH];   // K[key][d]
  __shared__ u16 Vs[64 * APITCH];   // V^T[d][key]
  __shared__ u16 Ps[64 * APITCH];   // P[q][key]
  __shared__ float red[2][64];      // per-key-half l partials

  const int tid  = threadIdx.x;
  const int lane = tid & 63;
  const int w    = tid >> 6;
  const int l31  = lane & 31;
  const int hh   = lane >> 5;        // lane half (0/1)
  const int kh   = w & 1;            // key-half for scores / d-half for PV
  const int qh   = w >> 1;           // q-half
  const int qb = blockIdx.x, h = blockIdx.y, b = blockIdx.z;

  // staging coords: thread stages rows sr, sr+32 of K[key][d] and Vt[d][key]
  const int sr = tid >> 3;           // 0..31
  const int sc = (tid & 7) * 8;      // col (x8 u16)

  // Q B-fragments, register-resident: B[k=d][n=q], lane: q=qh*32+l31,
  // d = ks*16 + 8*hh + j  -> Qb[row][h*64 + ...] b128 loads.
  const u16* qrow = Qb + (size_t)(b * S + qb * 64 + qh * 32 + l31) * HID + h * D;
  frag16 qf[4];
#pragma unroll
  for (int ks = 0; ks < 4; ++ks)
    qf[ks] = *(const frag16*)(qrow + ks * 16 + hh * 8);

  // Persistent zero accumulator for the first score-MFMA's C operand.
  f32x16 zero16;
#pragma unroll
  for (int r = 0; r < 16; ++r) zero16[r] = 0.f;

  f32x16 o_acc;
#pragma unroll
  for (int r = 0; r < 16; ++r) o_acc[r] = 0.f;
  float l_lane = 0.f;

  const u16* kbase = Kb + (size_t)(b * S) * D;   // K[key][d], key rel. to batch
  const u16* vbase = Vt + (size_t)(b * S);       // Vt[d][key]

  // ---- prologue: chunk 0 -> regs -> LDS ----
  frag16 pk0 = *(const frag16*)(kbase + (size_t)sr * D + sc);
  frag16 pk1 = *(const frag16*)(kbase + (size_t)(sr + 32) * D + sc);
  frag16 pv0 = *(const frag16*)(vbase + (size_t)sr * BS + sc);
  frag16 pv1 = *(const frag16*)(vbase + (size_t)(sr + 32) * BS + sc);
  *(frag16*)(&Ks[sr * APITCH + sc])        = pk0;
  *(frag16*)(&Ks[(sr + 32) * APITCH + sc]) = pk1;
  *(frag16*)(&Vs[sr * APITCH + sc])        = pv0;
  *(frag16*)(&Vs[(sr + 32) * APITCH + sc]) = pv1;
  __syncthreads();

  for (int kc = 0; kc < S; kc += 64) {
    // ---- issue next-chunk global loads (clamped re-load on last iter) ----
    const int nc = (kc + 64 < S) ? kc + 64 : kc;
    pk0 = *(const frag16*)(kbase + (size_t)(nc + sr) * D + sc);
    pk1 = *(const frag16*)(kbase + (size_t)(nc + sr + 32) * D + sc);
    pv0 = *(const frag16*)(vbase + (size_t)sr * BS + nc + sc);
    pv1 = *(const frag16*)(vbase + (size_t)(sr + 32) * BS + nc + sc);

    // ---- hoist V fragments for PV (so Ks/Vs are read-free after sync1) ----
    frag16 vf[4];
#pragma unroll
    for (int ks = 0; ks < 4; ++ks)
      vf[ks] = *(const frag16*)(&Vs[(kh * 32 + l31) * APITCH + ks * 16 + hh * 8]);

    // ---- S^T = K . Q^T : A[m=key]=Ks rows, B=Q regs; first MFMA C=zero16 ----
    f32x16 sa;
#pragma unroll
    for (int ks = 0; ks < 4; ++ks) {
      const frag16 kf = *(const frag16*)(&Ks[(kh * 32 + l31) * APITCH + ks * 16 + hh * 8]);
      sa = __builtin_amdgcn_mfma_f32_32x32x16_bf16(kf, qf[ks], ks ? sa : zero16, 0, 0, 0);
    }

    // ---- p = exp2(s) (scale pre-folded); lane's 16 vals: q = qh*32+l31,
    //      key = kh*32 + (r&3) + 8*(r>>2) + 4*hh  -> 4 runs of 4 ----
    const int qrow_l = qh * 32 + l31;
    u16* prow = &Ps[qrow_l * APITCH + kh * 32];
#pragma unroll
    for (int g = 0; g < 4; ++g) {
      const float p0 = __builtin_amdgcn_exp2f(sa[g * 4 + 0]);
      const float p1 = __builtin_amdgcn_exp2f(sa[g * 4 + 1]);
      const float p2 = __builtin_amdgcn_exp2f(sa[g * 4 + 2]);
      const float p3 = __builtin_amdgcn_exp2f(sa[g * 4 + 3]);
      l_lane += (p0 + p1) + (p2 + p3);
      uint2 pk;
      pk.x = cvt_pk_bf16(p0, p1);
      pk.y = cvt_pk_bf16(p2, p3);
      *(uint2*)(&prow[g * 8 + hh * 4]) = pk;
    }
    __syncthreads();  // sync1: Ps ready; all Ks/Vs reads of this chunk done

    // ---- PV: O[q][d] += P[q][k] V[k][d]; A=Ps[q][key] b128, B=vf regs ----
#pragma unroll
    for (int ks = 0; ks < 4; ++ks) {
      const frag16 pf = *(const frag16*)(&Ps[(qh * 32 + l31) * APITCH + ks * 16 + hh * 8]);
      o_acc = __builtin_amdgcn_mfma_f32_32x32x16_bf16(pf, vf[ks], o_acc, 0, 0, 0);
    }

    // ---- stage next chunk (prefetch regs -> LDS); no WAR barrier needed ----
    *(frag16*)(&Ks[sr * APITCH + sc])        = pk0;
    *(frag16*)(&Ks[(sr + 32) * APITCH + sc]) = pk1;
    *(frag16*)(&Vs[sr * APITCH + sc])        = pv0;
    *(frag16*)(&Vs[(sr + 32) * APITCH + sc]) = pv1;
    __syncthreads();  // sync2: KV ready for t+1; Ps write-safe for t+1
  }

  // ---- l reduction: lane+lane^32 (same q, complementary keys), then
  //      across the two key-half waves via LDS ----
  l_lane += __shfl_xor(l_lane, 32);
  __syncthreads();
  if (lane < 32) red[kh][qh * 32 + l31] = l_lane;
  __syncthreads();

  // ---- epilogue: O C-layout col=d=l31(+kh*32), row q per reg pattern ----
#pragma unroll
  for (int r = 0; r < 16; ++r) {
    const int q_local = qh * 32 + (r & 3) + 8 * (r >> 2) + 4 * hh;
    const float li = 1.f / (red[0][q_local] + red[1][q_local]);
    u16* orow = O + (size_t)(b * S + qb * 64 + q_local) * HID + h * D;
    orow[kh * 32 + l31] = f2bf(o_acc[r] * li);
  }
}

extern "C" void kernel_launch(void* const* d_in, const int* in_sizes, int n_in,
                              void* d_out, int out_size, void* d_ws, size_t ws_size,
                              hipStream_t stream) {
  const float* query = (const float*)d_in[0];
  const float* key   = (const float*)d_in[1];
  const float* value = (const float*)d_in[2];
  const float* Wq    = (const float*)d_in[3];
  const float* bq    = (const float*)d_in[4];
  const float* Wk    = (const float*)d_in[5];
  const float* bk    = (const float*)d_in[6];
  const float* Wv    = (const float*)d_in[7];
  const float* bv    = (const float*)d_in[8];
  const float* Wo    = (const float*)d_in[9];
  const float* bo    = (const float*)d_in[10];
  float* out = (float*)d_out;

  const int B = 2, S = 2048, IN = 1024, HID = 1024, H = 16, D = 64;
  const int M = B * S;  // 4096
  const size_t MB = 1024 * 1024;

  char* ws = (char*)d_ws;
  u16* q_bf  = (u16*)ws;                           // [0, 8MB)
  u16* ao_bf = (u16*)(ws + 8 * MB);                // [8, 16MB)
  u16* k_bf  = (u16*)(ws + 16 * MB);               // 0.5 MB
  u16* vt_bf = (u16*)(ws + 16 * MB + 512 * 1024);  // 0.5 MB
  u16* wq_t  = (u16*)(ws + 17 * MB);               // 2 MB [1024][1024]
  u16* wo_t  = (u16*)(ws + 19 * MB);               // 2 MB [1024][1024]
  u16* wk_t  = (u16*)(ws + 21 * MB);               // 128 KB [64][1024]
  u16* wv_t  = (u16*)(ws + 21 * MB + 128 * 1024);  // 128 KB [64][1024]

  dim3 blk(256);
  prep_w<<<dim3(544), blk, 0, stream>>>(Wq, Wo, Wk, Wv, wq_t, wo_t, wk_t, wv_t);
  proj<<<dim3(1152), blk, 0, stream>>>(query, key, value, wq_t, wk_t, wv_t,
                                       bq, bk, bv, q_bf, k_bf, vt_bf, M, IN);
  mqa_flash_mfma<<<dim3(S / 64, H, B), blk, 0, stream>>>(q_bf, k_bf, vt_bf, ao_bf);
  out_proj<<<dim3(HID / 64, M / 64), blk, 0, stream>>>(ao_bf, wo_t, bo, out, M, HID);
}

// Round 3
// 208.764 us; speedup vs baseline: 1.1442x; 1.0371x over previous
//
#include <hip/hip_runtime.h>

// ---------------------------------------------------------------------------
// MQA: out = softmax((X Wq)(X Wk)^T / 32)(X Wv) Wo, MQA broadcast K/V.
// B=2, S=2048, IN=HID=1024, H=16, D=64.
// Round 11: the two 1024-wide GEMMs (Q-proj, out-proj) rewritten on the m97
// 128^2-tile structure (BK=64, global_load_lds width=16, 2-barrier loop,
// 4 waves x 64x64 output, 4x4 16x16x32 frags) — measured 874-912 TF vs
// ~343 TF for the old 64^2 gemm64 (learn_hip ladder steps 2->3).
//   - query pre-converted fp32->bf16 (xq_bf) by 1024 extra blocks in prep_w
//     so A can be staged with global_load_lds; xq_bf shares the ao_bf slot
//     (disjoint live ranges: prep->proj vs mqa->out_proj).
//   - K/V projections (N=64) stay on gemm64, same proj2 launch.
// mqa_flash_mfma unchanged from Round 10 (57 us; next target).
// ---------------------------------------------------------------------------

typedef unsigned int   u32;
typedef unsigned short u16;
typedef union { float4 v; float f[4]; } f4u;
typedef __attribute__((ext_vector_type(8)))  short frag16;  // 8 bf16 (4 VGPR)
typedef __attribute__((ext_vector_type(4)))  float f32x4;
typedef __attribute__((ext_vector_type(16))) float f32x16;  // 32x32 MFMA acc
typedef union { frag16 v; u32 w[4]; u16 e[8]; } bf8u;

static __device__ __forceinline__ u16 f2bf(float x) {
  union { float f; u32 u; } v; v.f = x;
  u32 r = v.u + 0x7fff + ((v.u >> 16) & 1);   // RNE
  return (u16)(r >> 16);
}

// HW packed f32x2 -> bf16x2 convert (RNE), inline asm (no builtin on gfx950).
static __device__ __forceinline__ u32 cvt_pk_bf16(float lo, float hi) {
  u32 r;
  asm("v_cvt_pk_bf16_f32 %0, %1, %2" : "=v"(r) : "v"(lo), "v"(hi));
  return r;
}

// Async global->LDS, 16B per lane. LDS dest = wave-uniform base + lane*16.
static __device__ __forceinline__ void gload_lds16(const u16* g, u16* l) {
  __builtin_amdgcn_global_load_lds(
      (const __attribute__((address_space(1))) u32*)g,
      (__attribute__((address_space(3))) u32*)l, 16, 0, 0);
}

// ---------------------------------------------------------------------------
// prep_w: weight transpose+convert tiles (blocks 0..543) + query fp32->bf16
// elementwise convert (blocks 544..1567; 4096 elems/block).
// ---------------------------------------------------------------------------
static __device__ void tcvt_tile(const float* __restrict__ src,
                                 u16* __restrict__ dst,
                                 int C, int ldT, int rt, int ct,
                                 float (*t)[65]) {
  const int r0 = rt * 64, c0 = ct * 64;
  const int tr  = threadIdx.x >> 4;
  const int tc4 = (threadIdx.x & 15) * 4;
#pragma unroll
  for (int i = 0; i < 4; ++i) {
    f4u v; v.v = *(const float4*)(src + (size_t)(r0 + tr + i * 16) * C + c0 + tc4);
    t[tr + i * 16][tc4 + 0] = v.f[0];
    t[tr + i * 16][tc4 + 1] = v.f[1];
    t[tr + i * 16][tc4 + 2] = v.f[2];
    t[tr + i * 16][tc4 + 3] = v.f[3];
  }
  __syncthreads();
#pragma unroll
  for (int i = 0; i < 4; ++i) {
    const int oc = tr + i * 16;
    ushort4 o;
    o.x = f2bf(t[tc4 + 0][oc]);
    o.y = f2bf(t[tc4 + 1][oc]);
    o.z = f2bf(t[tc4 + 2][oc]);
    o.w = f2bf(t[tc4 + 3][oc]);
    *(ushort4*)(dst + (size_t)(c0 + oc) * ldT + r0 + tc4) = o;
  }
}

__global__ __launch_bounds__(256)
void prep_w(const float* __restrict__ Wq, const float* __restrict__ Wo,
            const float* __restrict__ Wk, const float* __restrict__ Wv,
            const float* __restrict__ query,
            u16* __restrict__ wq_t, u16* __restrict__ wo_t,
            u16* __restrict__ wk_t, u16* __restrict__ wv_t,
            u16* __restrict__ xq_bf) {
  const int bid = blockIdx.x;
  if (bid >= 544) {
    // query fp32 -> bf16, 16 elems/thread
    const size_t base = (size_t)(bid - 544) * 4096 + threadIdx.x * 16;
    f4u x0, x1, x2, x3;
    x0.v = *(const float4*)(query + base);
    x1.v = *(const float4*)(query + base + 4);
    x2.v = *(const float4*)(query + base + 8);
    x3.v = *(const float4*)(query + base + 12);
    bf8u t0, t1;
    t0.w[0] = cvt_pk_bf16(x0.f[0], x0.f[1]);
    t0.w[1] = cvt_pk_bf16(x0.f[2], x0.f[3]);
    t0.w[2] = cvt_pk_bf16(x1.f[0], x1.f[1]);
    t0.w[3] = cvt_pk_bf16(x1.f[2], x1.f[3]);
    t1.w[0] = cvt_pk_bf16(x2.f[0], x2.f[1]);
    t1.w[1] = cvt_pk_bf16(x2.f[2], x2.f[3]);
    t1.w[2] = cvt_pk_bf16(x3.f[0], x3.f[1]);
    t1.w[3] = cvt_pk_bf16(x3.f[2], x3.f[3]);
    *(frag16*)(xq_bf + base)     = t0.v;
    *(frag16*)(xq_bf + base + 8) = t1.v;
    return;
  }
  __shared__ float t[64][65];
  if (bid < 256)      tcvt_tile(Wq, wq_t, 1024, 1024, bid >> 4, bid & 15, t);
  else if (bid < 512) tcvt_tile(Wo, wo_t, 1024, 1024, (bid - 256) >> 4, (bid - 256) & 15, t);
  else if (bid < 528) tcvt_tile(Wk, wk_t, 64, 1024, bid - 512, 0, t);
  else                tcvt_tile(Wv, wv_t, 64, 1024, bid - 528, 0, t);
}

// ---------------------------------------------------------------------------
// gemm128: m97-structure 128x128-tile bf16 GEMM. C = A[M,K] . Bt[N,K]^T.
// 256 thr = 4 waves (2x2), each wave 64x64 out (4x4 16x16x32 frags).
// LDS: As[128][64], Bs[128][64] linear (global_load_lds needs linear dest).
// Staging: per K-step 16 segments of 1024B each per operand; wave w stages
// segments 4w..4w+3 (lane l -> row seg*8 + l/8, cols (l%8)*8).
// ---------------------------------------------------------------------------
static __device__ void gemm128(const u16* __restrict__ Abf,
                               const u16* __restrict__ Bt,
                               const float* __restrict__ bias,
                               void* __restrict__ Cout, int out_mode,
                               float oscale, int row0, int col0,
                               int N, int K, u16* As, u16* Bs) {
  const int tid  = threadIdx.x;
  const int lane = tid & 63;
  const int quad = lane >> 4, l15 = lane & 15;
  const int w = tid >> 6, wy = w >> 1, wx = w & 1;
  const int lrow = lane >> 3, lcol = (lane & 7) * 8;

  f32x4 acc[4][4];
#pragma unroll
  for (int i = 0; i < 4; ++i)
#pragma unroll
    for (int j = 0; j < 4; ++j) {
      acc[i][j][0] = 0.f; acc[i][j][1] = 0.f;
      acc[i][j][2] = 0.f; acc[i][j][3] = 0.f;
    }

  const u16* ag = Abf + (size_t)(row0 + w * 32 + lrow) * K + lcol;  // per-lane
  const u16* bg = Bt  + (size_t)(col0 + w * 32 + lrow) * K + lcol;
  u16* alds = As + w * 4 * 512;   // wave-uniform segment base
  u16* blds = Bs + w * 4 * 512;

  for (int k0 = 0; k0 < K; k0 += 64) {
    __syncthreads();   // prev compute's LDS reads done (WAR)
#pragma unroll
    for (int i = 0; i < 4; ++i) {
      gload_lds16(ag + (size_t)i * 8 * K + k0, alds + i * 512);
      gload_lds16(bg + (size_t)i * 8 * K + k0, blds + i * 512);
    }
    __syncthreads();   // staging visible (compiler drains vmcnt before barrier)
#pragma unroll
    for (int ks = 0; ks < 2; ++ks) {
      frag16 af[4], bfr[4];
#pragma unroll
      for (int i = 0; i < 4; ++i)
        af[i] = *(const frag16*)(&As[(wy * 64 + i * 16 + l15) * 64 + ks * 32 + quad * 8]);
#pragma unroll
      for (int j = 0; j < 4; ++j)
        bfr[j] = *(const frag16*)(&Bs[(wx * 64 + j * 16 + l15) * 64 + ks * 32 + quad * 8]);
#pragma unroll
      for (int i = 0; i < 4; ++i)
#pragma unroll
        for (int j = 0; j < 4; ++j)
          acc[i][j] = __builtin_amdgcn_mfma_f32_16x16x32_bf16(af[i], bfr[j], acc[i][j], 0, 0, 0);
    }
  }

  float bj[4];
#pragma unroll
  for (int j = 0; j < 4; ++j)
    bj[j] = bias[col0 + wx * 64 + j * 16 + l15];

#pragma unroll
  for (int i = 0; i < 4; ++i)
#pragma unroll
    for (int rr = 0; rr < 4; ++rr) {
      const size_t row = row0 + wy * 64 + i * 16 + quad * 4 + rr;
#pragma unroll
      for (int j = 0; j < 4; ++j) {
        const float v = (acc[i][j][rr] + bj[j]) * oscale;
        const int col = col0 + wx * 64 + j * 16 + l15;
        if (out_mode == 0) ((float*)Cout)[row * N + col] = v;
        else               ((u16*)Cout)[row * N + col] = f2bf(v);
      }
    }
}

// ---------------------------------------------------------------------------
// gemm64: 64x64-tile GEMM (kept for the N=64 K/V projections; fp32 A path).
// ---------------------------------------------------------------------------
#define GP 72
template <bool A_FP32>
static __device__ void gemm64(const float* __restrict__ Af32,
                              const u16* __restrict__ Abf,
                              const u16* __restrict__ Bt,
                              const float* __restrict__ bias,
                              void* __restrict__ Cout, int out_mode,
                              float oscale,
                              int row0, int col0, int N, int K, int ldT,
                              u16* As, u16* Bs) {
  const int tid  = threadIdx.x;
  const int lane = tid & 63;
  const int quad = lane >> 4, l15 = lane & 15;
  const int w = tid >> 6, wy = w >> 1, wx = w & 1;

  f32x4 acc[2][2];
#pragma unroll
  for (int i = 0; i < 2; ++i)
#pragma unroll
    for (int j = 0; j < 2; ++j) {
      acc[i][j][0] = 0.f; acc[i][j][1] = 0.f;
      acc[i][j][2] = 0.f; acc[i][j][3] = 0.f;
    }

  const int r = tid >> 2, c16 = (tid & 3) * 16;

  for (int k0 = 0; k0 < K; k0 += 64) {
    frag16 a0, a1;
    if (A_FP32) {
      const float* ap = Af32 + (size_t)(row0 + r) * K + k0 + c16;
      f4u x0, x1, x2, x3;
      x0.v = *(const float4*)(ap);
      x1.v = *(const float4*)(ap + 4);
      x2.v = *(const float4*)(ap + 8);
      x3.v = *(const float4*)(ap + 12);
      bf8u t0, t1;
      t0.w[0] = cvt_pk_bf16(x0.f[0], x0.f[1]);
      t0.w[1] = cvt_pk_bf16(x0.f[2], x0.f[3]);
      t0.w[2] = cvt_pk_bf16(x1.f[0], x1.f[1]);
      t0.w[3] = cvt_pk_bf16(x1.f[2], x1.f[3]);
      t1.w[0] = cvt_pk_bf16(x2.f[0], x2.f[1]);
      t1.w[1] = cvt_pk_bf16(x2.f[2], x2.f[3]);
      t1.w[2] = cvt_pk_bf16(x3.f[0], x3.f[1]);
      t1.w[3] = cvt_pk_bf16(x3.f[2], x3.f[3]);
      a0 = t0.v; a1 = t1.v;
    } else {
      const u16* ap = Abf + (size_t)(row0 + r) * K + k0 + c16;
      a0 = *(const frag16*)(ap);
      a1 = *(const frag16*)(ap + 8);
    }
    const u16* bp = Bt + (size_t)(col0 + r) * K + k0 + c16;
    const frag16 b0 = *(const frag16*)(bp);
    const frag16 b1 = *(const frag16*)(bp + 8);
    __syncthreads();
    *(frag16*)(&As[r * GP + c16])     = a0;
    *(frag16*)(&As[r * GP + c16 + 8]) = a1;
    *(frag16*)(&Bs[r * GP + c16])     = b0;
    *(frag16*)(&Bs[r * GP + c16 + 8]) = b1;
    __syncthreads();
#pragma unroll
    for (int ks = 0; ks < 2; ++ks) {
      frag16 af[2], bf[2];
#pragma unroll
      for (int i = 0; i < 2; ++i)
        af[i] = *(const frag16*)(&As[(wy * 32 + i * 16 + l15) * GP + ks * 32 + quad * 8]);
#pragma unroll
      for (int j = 0; j < 2; ++j)
        bf[j] = *(const frag16*)(&Bs[(wx * 32 + j * 16 + l15) * GP + ks * 32 + quad * 8]);
#pragma unroll
      for (int i = 0; i < 2; ++i)
#pragma unroll
        for (int j = 0; j < 2; ++j)
          acc[i][j] = __builtin_amdgcn_mfma_f32_16x16x32_bf16(af[i], bf[j], acc[i][j], 0, 0, 0);
    }
  }

  float bj[2];
#pragma unroll
  for (int j = 0; j < 2; ++j)
    bj[j] = bias[col0 + wx * 32 + j * 16 + l15];

#pragma unroll
  for (int i = 0; i < 2; ++i) {
#pragma unroll
    for (int rr = 0; rr < 4; ++rr) {
      const size_t row = row0 + wy * 32 + i * 16 + quad * 4 + rr;
#pragma unroll
      for (int j = 0; j < 2; ++j) {
        const float v = (acc[i][j][rr] + bj[j]) * oscale;
        const int col = col0 + wx * 32 + j * 16 + l15;
        if (out_mode == 0)      ((float*)Cout)[row * N + col] = v;
        else if (out_mode == 1) ((u16*)Cout)[row * N + col] = f2bf(v);
        else                    ((u16*)Cout)[(size_t)col * ldT + row] = f2bf(v);
      }
    }
  }
}

#define C2_SCALE 0.045084220027780106f   // log2(e)/32, folded into Q-proj

// blocks 0..255: Q-proj gemm128 tiles; 256..319: K-proj; 320..383: V-proj.
__global__ __launch_bounds__(256, 3)
void proj2(const float* __restrict__ key, const float* __restrict__ value,
           const u16* __restrict__ xq_bf,
           const u16* __restrict__ wq_t, const u16* __restrict__ wk_t,
           const u16* __restrict__ wv_t,
           const float* __restrict__ bq, const float* __restrict__ bk,
           const float* __restrict__ bv,
           u16* __restrict__ q_bf, u16* __restrict__ k_bf,
           u16* __restrict__ vt_bf, int M, int K) {
  __shared__ __align__(16) u16 smem[16384];   // 32 KB
  const int bid = blockIdx.x;
  if (bid < 256)
    gemm128(xq_bf, wq_t, bq, q_bf, 1, C2_SCALE,
            (bid >> 3) * 128, (bid & 7) * 128, 1024, K, smem, smem + 8192);
  else if (bid < 320)
    gemm64<true>(key, nullptr, wk_t, bk, k_bf, 1, 1.0f,
                 (bid - 256) * 64, 0, 64, K, 0, smem, smem + 64 * GP);
  else
    gemm64<true>(value, nullptr, wv_t, bv, vt_bf, 2, 1.0f,
                 (bid - 320) * 64, 0, 64, K, M, smem, smem + 64 * GP);
}

__global__ __launch_bounds__(256, 3)
void out_proj(const u16* __restrict__ ao, const u16* __restrict__ wo_t,
              const float* __restrict__ bo, float* __restrict__ out,
              int M, int K) {
  __shared__ __align__(16) u16 smem[16384];
  const int bid = blockIdx.x;
  gemm128(ao, wo_t, bo, out, 0, 1.0f,
          (bid >> 3) * 128, (bid & 7) * 128, 1024, K, smem, smem + 8192);
}

// ---------------------------------------------------------------------------
// Flash MQA attention (unchanged from Round 10): mfma_32x32x16, S^T trick,
// 2-barrier pipeline with T14 async-STAGE and reg-hoisted V frags.
// ---------------------------------------------------------------------------
#define APITCH 72

__global__ __launch_bounds__(256, 4)
void mqa_flash_mfma(const u16* __restrict__ Qb,  // [B,S,1024] bf16 (pre-scaled by C2)
                    const u16* __restrict__ Kb,  // [B,S,64]   bf16
                    const u16* __restrict__ Vt,  // [64][B*S]  bf16 (transposed)
                    u16* __restrict__ O) {       // [B,S,1024] bf16
  const int S = 2048, HID = 1024, D = 64, BS = 4096;
  __shared__ u16 Ks[64 * APITCH];   // K[key][d]
  __shared__ u16 Vs[64 * APITCH];   // V^T[d][key]
  __shared__ u16 Ps[64 * APITCH];   // P[q][key]
  __shared__ float red[2][64];      // per-key-half l partials

  const int tid  = threadIdx.x;
  const int lane = tid & 63;
  const int w    = tid >> 6;
  const int l31  = lane & 31;
  const int hh   = lane >> 5;        // lane half (0/1)
  const int kh   = w & 1;            // key-half for scores / d-half for PV
  const int qh   = w >> 1;           // q-half
  const int qb = blockIdx.x, h = blockIdx.y, b = blockIdx.z;

  const int sr = tid >> 3;           // 0..31
  const int sc = (tid & 7) * 8;      // col (x8 u16)

  const u16* qrow = Qb + (size_t)(b * S + qb * 64 + qh * 32 + l31) * HID + h * D;
  frag16 qf[4];
#pragma unroll
  for (int ks = 0; ks < 4; ++ks)
    qf[ks] = *(const frag16*)(qrow + ks * 16 + hh * 8);

  f32x16 zero16;
#pragma unroll
  for (int r = 0; r < 16; ++r) zero16[r] = 0.f;

  f32x16 o_acc;
#pragma unroll
  for (int r = 0; r < 16; ++r) o_acc[r] = 0.f;
  float l_lane = 0.f;

  const u16* kbase = Kb + (size_t)(b * S) * D;   // K[key][d], key rel. to batch
  const u16* vbase = Vt + (size_t)(b * S);       // Vt[d][key]

  // ---- prologue: chunk 0 -> regs -> LDS ----
  frag16 pk0 = *(const frag16*)(kbase + (size_t)sr * D + sc);
  frag16 pk1 = *(const frag16*)(kbase + (size_t)(sr + 32) * D + sc);
  frag16 pv0 = *(const frag16*)(vbase + (size_t)sr * BS + sc);
  frag16 pv1 = *(const frag16*)(vbase + (size_t)(sr + 32) * BS + sc);
  *(frag16*)(&Ks[sr * APITCH + sc])        = pk0;
  *(frag16*)(&Ks[(sr + 32) * APITCH + sc]) = pk1;
  *(frag16*)(&Vs[sr * APITCH + sc])        = pv0;
  *(frag16*)(&Vs[(sr + 32) * APITCH + sc]) = pv1;
  __syncthreads();

  for (int kc = 0; kc < S; kc += 64) {
    const int nc = (kc + 64 < S) ? kc + 64 : kc;
    pk0 = *(const frag16*)(kbase + (size_t)(nc + sr) * D + sc);
    pk1 = *(const frag16*)(kbase + (size_t)(nc + sr + 32) * D + sc);
    pv0 = *(const frag16*)(vbase + (size_t)sr * BS + nc + sc);
    pv1 = *(const frag16*)(vbase + (size_t)(sr + 32) * BS + nc + sc);

    frag16 vf[4];
#pragma unroll
    for (int ks = 0; ks < 4; ++ks)
      vf[ks] = *(const frag16*)(&Vs[(kh * 32 + l31) * APITCH + ks * 16 + hh * 8]);

    f32x16 sa;
#pragma unroll
    for (int ks = 0; ks < 4; ++ks) {
      const frag16 kf = *(const frag16*)(&Ks[(kh * 32 + l31) * APITCH + ks * 16 + hh * 8]);
      sa = __builtin_amdgcn_mfma_f32_32x32x16_bf16(kf, qf[ks], ks ? sa : zero16, 0, 0, 0);
    }

    const int qrow_l = qh * 32 + l31;
    u16* prow = &Ps[qrow_l * APITCH + kh * 32];
#pragma unroll
    for (int g = 0; g < 4; ++g) {
      const float p0 = __builtin_amdgcn_exp2f(sa[g * 4 + 0]);
      const float p1 = __builtin_amdgcn_exp2f(sa[g * 4 + 1]);
      const float p2 = __builtin_amdgcn_exp2f(sa[g * 4 + 2]);
      const float p3 = __builtin_amdgcn_exp2f(sa[g * 4 + 3]);
      l_lane += (p0 + p1) + (p2 + p3);
      uint2 pk;
      pk.x = cvt_pk_bf16(p0, p1);
      pk.y = cvt_pk_bf16(p2, p3);
      *(uint2*)(&prow[g * 8 + hh * 4]) = pk;
    }
    __syncthreads();  // sync1: Ps ready; all Ks/Vs reads of this chunk done

#pragma unroll
    for (int ks = 0; ks < 4; ++ks) {
      const frag16 pf = *(const frag16*)(&Ps[(qh * 32 + l31) * APITCH + ks * 16 + hh * 8]);
      o_acc = __builtin_amdgcn_mfma_f32_32x32x16_bf16(pf, vf[ks], o_acc, 0, 0, 0);
    }

    *(frag16*)(&Ks[sr * APITCH + sc])        = pk0;
    *(frag16*)(&Ks[(sr + 32) * APITCH + sc]) = pk1;
    *(frag16*)(&Vs[sr * APITCH + sc])        = pv0;
    *(frag16*)(&Vs[(sr + 32) * APITCH + sc]) = pv1;
    __syncthreads();  // sync2: KV ready for t+1; Ps write-safe for t+1
  }

  l_lane += __shfl_xor(l_lane, 32);
  __syncthreads();
  if (lane < 32) red[kh][qh * 32 + l31] = l_lane;
  __syncthreads();

#pragma unroll
  for (int r = 0; r < 16; ++r) {
    const int q_local = qh * 32 + (r & 3) + 8 * (r >> 2) + 4 * hh;
    const float li = 1.f / (red[0][q_local] + red[1][q_local]);
    u16* orow = O + (size_t)(b * S + qb * 64 + q_local) * HID + h * D;
    orow[kh * 32 + l31] = f2bf(o_acc[r] * li);
  }
}

extern "C" void kernel_launch(void* const* d_in, const int* in_sizes, int n_in,
                              void* d_out, int out_size, void* d_ws, size_t ws_size,
                              hipStream_t stream) {
  const float* query = (const float*)d_in[0];
  const float* key   = (const float*)d_in[1];
  const float* value = (const float*)d_in[2];
  const float* Wq    = (const float*)d_in[3];
  const float* bq    = (const float*)d_in[4];
  const float* Wk    = (const float*)d_in[5];
  const float* bk    = (const float*)d_in[6];
  const float* Wv    = (const float*)d_in[7];
  const float* bv    = (const float*)d_in[8];
  const float* Wo    = (const float*)d_in[9];
  const float* bo    = (const float*)d_in[10];
  float* out = (float*)d_out;

  const int B = 2, S = 2048, IN = 1024, HID = 1024, H = 16, D = 64;
  const int M = B * S;  // 4096
  const size_t MB = 1024 * 1024;

  char* ws = (char*)d_ws;
  u16* q_bf  = (u16*)ws;                           // [0, 8MB)
  u16* ao_bf = (u16*)(ws + 8 * MB);                // [8, 16MB)  (mqa -> out_proj)
  u16* xq_bf = ao_bf;                              // same slot (prep -> proj2)
  u16* k_bf  = (u16*)(ws + 16 * MB);               // 0.5 MB
  u16* vt_bf = (u16*)(ws + 16 * MB + 512 * 1024);  // 0.5 MB
  u16* wq_t  = (u16*)(ws + 17 * MB);               // 2 MB [1024][1024]
  u16* wo_t  = (u16*)(ws + 19 * MB);               // 2 MB [1024][1024]
  u16* wk_t  = (u16*)(ws + 21 * MB);               // 128 KB [64][1024]
  u16* wv_t  = (u16*)(ws + 21 * MB + 128 * 1024);  // 128 KB [64][1024]

  dim3 blk(256);
  prep_w<<<dim3(1568), blk, 0, stream>>>(Wq, Wo, Wk, Wv, query,
                                         wq_t, wo_t, wk_t, wv_t, xq_bf);
  proj2<<<dim3(384), blk, 0, stream>>>(key, value, xq_bf, wq_t, wk_t, wv_t,
                                       bq, bk, bv, q_bf, k_bf, vt_bf, M, IN);
  mqa_flash_mfma<<<dim3(S / 64, H, B), blk, 0, stream>>>(q_bf, k_bf, vt_bf, ao_bf);
  out_proj<<<dim3(256), blk, 0, stream>>>(ao_bf, wo_t, bo, out, M, HID);
}

// Round 5
// 208.405 us; speedup vs baseline: 1.1462x; 1.0017x over previous
//
#include <hip/hip_runtime.h>

// ---------------------------------------------------------------------------
// MQA: out = softmax((X Wq)(X Wk)^T / 32)(X Wv) Wo, MQA broadcast K/V.
// B=2, S=2048, IN=HID=1024, H=16, D=64.
// Round 13 (bisect): R12 failed (absmax 4e20) with two simultaneous changes.
//   - mqa_flash_mfma REVERTED to the exact Round-10 body (verified, 57.2us):
//     S^T trick, 2-barrier T14 pipeline, P via LDS.
//   - proj2/out_proj KEEP R12's 128x64-tile gemm128n64 (faithful shrink of
//     verified R11 gemm128; 512+ blocks = 2 blocks/CU so barrier drains are
//     covered by co-resident blocks, m114).
// If this passes: R12's mqa in-register-P path was the bug. If it fails:
// gemm128n64 is the bug.
// ---------------------------------------------------------------------------

typedef unsigned int   u32;
typedef unsigned short u16;
typedef union { float4 v; float f[4]; } f4u;
typedef __attribute__((ext_vector_type(8)))  short frag16;  // 8 bf16 (4 VGPR)
typedef __attribute__((ext_vector_type(4)))  float f32x4;
typedef __attribute__((ext_vector_type(16))) float f32x16;  // 32x32 MFMA acc
typedef union { frag16 v; u32 w[4]; u16 e[8]; } bf8u;

static __device__ __forceinline__ u16 f2bf(float x) {
  union { float f; u32 u; } v; v.f = x;
  u32 r = v.u + 0x7fff + ((v.u >> 16) & 1);   // RNE
  return (u16)(r >> 16);
}

// HW packed f32x2 -> bf16x2 convert (RNE), inline asm (no builtin on gfx950).
static __device__ __forceinline__ u32 cvt_pk_bf16(float lo, float hi) {
  u32 r;
  asm("v_cvt_pk_bf16_f32 %0, %1, %2" : "=v"(r) : "v"(lo), "v"(hi));
  return r;
}

// Async global->LDS, 16B per lane. LDS dest = wave-uniform base + lane*16.
static __device__ __forceinline__ void gload_lds16(const u16* g, u16* l) {
  __builtin_amdgcn_global_load_lds(
      (const __attribute__((address_space(1))) u32*)g,
      (__attribute__((address_space(3))) u32*)l, 16, 0, 0);
}

// ---------------------------------------------------------------------------
// prep_w: weight transpose+convert tiles (blocks 0..543) + query fp32->bf16
// elementwise convert (blocks 544..1567; 4096 elems/block).
// ---------------------------------------------------------------------------
static __device__ void tcvt_tile(const float* __restrict__ src,
                                 u16* __restrict__ dst,
                                 int C, int ldT, int rt, int ct,
                                 float (*t)[65]) {
  const int r0 = rt * 64, c0 = ct * 64;
  const int tr  = threadIdx.x >> 4;
  const int tc4 = (threadIdx.x & 15) * 4;
#pragma unroll
  for (int i = 0; i < 4; ++i) {
    f4u v; v.v = *(const float4*)(src + (size_t)(r0 + tr + i * 16) * C + c0 + tc4);
    t[tr + i * 16][tc4 + 0] = v.f[0];
    t[tr + i * 16][tc4 + 1] = v.f[1];
    t[tr + i * 16][tc4 + 2] = v.f[2];
    t[tr + i * 16][tc4 + 3] = v.f[3];
  }
  __syncthreads();
#pragma unroll
  for (int i = 0; i < 4; ++i) {
    const int oc = tr + i * 16;
    ushort4 o;
    o.x = f2bf(t[tc4 + 0][oc]);
    o.y = f2bf(t[tc4 + 1][oc]);
    o.z = f2bf(t[tc4 + 2][oc]);
    o.w = f2bf(t[tc4 + 3][oc]);
    *(ushort4*)(dst + (size_t)(c0 + oc) * ldT + r0 + tc4) = o;
  }
}

__global__ __launch_bounds__(256)
void prep_w(const float* __restrict__ Wq, const float* __restrict__ Wo,
            const float* __restrict__ Wk, const float* __restrict__ Wv,
            const float* __restrict__ query,
            u16* __restrict__ wq_t, u16* __restrict__ wo_t,
            u16* __restrict__ wk_t, u16* __restrict__ wv_t,
            u16* __restrict__ xq_bf) {
  const int bid = blockIdx.x;
  if (bid >= 544) {
    const size_t base = (size_t)(bid - 544) * 4096 + threadIdx.x * 16;
    f4u x0, x1, x2, x3;
    x0.v = *(const float4*)(query + base);
    x1.v = *(const float4*)(query + base + 4);
    x2.v = *(const float4*)(query + base + 8);
    x3.v = *(const float4*)(query + base + 12);
    bf8u t0, t1;
    t0.w[0] = cvt_pk_bf16(x0.f[0], x0.f[1]);
    t0.w[1] = cvt_pk_bf16(x0.f[2], x0.f[3]);
    t0.w[2] = cvt_pk_bf16(x1.f[0], x1.f[1]);
    t0.w[3] = cvt_pk_bf16(x1.f[2], x1.f[3]);
    t1.w[0] = cvt_pk_bf16(x2.f[0], x2.f[1]);
    t1.w[1] = cvt_pk_bf16(x2.f[2], x2.f[3]);
    t1.w[2] = cvt_pk_bf16(x3.f[0], x3.f[1]);
    t1.w[3] = cvt_pk_bf16(x3.f[2], x3.f[3]);
    *(frag16*)(xq_bf + base)     = t0.v;
    *(frag16*)(xq_bf + base + 8) = t1.v;
    return;
  }
  __shared__ float t[64][65];
  if (bid < 256)      tcvt_tile(Wq, wq_t, 1024, 1024, bid >> 4, bid & 15, t);
  else if (bid < 512) tcvt_tile(Wo, wo_t, 1024, 1024, (bid - 256) >> 4, (bid - 256) & 15, t);
  else if (bid < 528) tcvt_tile(Wk, wk_t, 64, 1024, bid - 512, 0, t);
  else                tcvt_tile(Wv, wv_t, 64, 1024, bid - 528, 0, t);
}

// ---------------------------------------------------------------------------
// gemm128n64: m97-structure 128x64-tile bf16 GEMM. C = A[M,K] . Bt[N,K]^T.
// 256 thr = 4 waves (2x2), each wave 64x32 out (4x2 16x16x32 frags).
// LDS: As[128][64] 16KB, Bs[64][64] 8KB, linear (global_load_lds dest).
// ---------------------------------------------------------------------------
static __device__ void gemm128n64(const u16* __restrict__ Abf,
                                  const u16* __restrict__ Bt,
                                  const float* __restrict__ bias,
                                  void* __restrict__ Cout, int out_mode,
                                  float oscale, int row0, int col0,
                                  int N, int K, u16* As, u16* Bs) {
  const int tid  = threadIdx.x;
  const int lane = tid & 63;
  const int quad = lane >> 4, l15 = lane & 15;
  const int w = tid >> 6, wy = w >> 1, wx = w & 1;
  const int lrow = lane >> 3, lcol = (lane & 7) * 8;

  f32x4 acc[4][2];
#pragma unroll
  for (int i = 0; i < 4; ++i)
#pragma unroll
    for (int j = 0; j < 2; ++j) {
      acc[i][j][0] = 0.f; acc[i][j][1] = 0.f;
      acc[i][j][2] = 0.f; acc[i][j][3] = 0.f;
    }

  const u16* ag = Abf + (size_t)(row0 + w * 32 + lrow) * K + lcol;  // per-lane
  const u16* bg = Bt  + (size_t)(col0 + w * 16 + lrow) * K + lcol;
  u16* alds = As + w * 4 * 512;   // wave-uniform segment base (A: segs 4w..4w+3)
  u16* blds = Bs + w * 2 * 512;   // B: segs 2w..2w+1

  for (int k0 = 0; k0 < K; k0 += 64) {
    __syncthreads();   // prev compute's LDS reads done (WAR)
#pragma unroll
    for (int i = 0; i < 4; ++i)
      gload_lds16(ag + (size_t)i * 8 * K + k0, alds + i * 512);
#pragma unroll
    for (int i = 0; i < 2; ++i)
      gload_lds16(bg + (size_t)i * 8 * K + k0, blds + i * 512);
    __syncthreads();   // staging visible
#pragma unroll
    for (int ks = 0; ks < 2; ++ks) {
      frag16 af[4], bfr[2];
#pragma unroll
      for (int i = 0; i < 4; ++i)
        af[i] = *(const frag16*)(&As[(wy * 64 + i * 16 + l15) * 64 + ks * 32 + quad * 8]);
#pragma unroll
      for (int j = 0; j < 2; ++j)
        bfr[j] = *(const frag16*)(&Bs[(wx * 32 + j * 16 + l15) * 64 + ks * 32 + quad * 8]);
#pragma unroll
      for (int i = 0; i < 4; ++i)
#pragma unroll
        for (int j = 0; j < 2; ++j)
          acc[i][j] = __builtin_amdgcn_mfma_f32_16x16x32_bf16(af[i], bfr[j], acc[i][j], 0, 0, 0);
    }
  }

  float bj[2];
#pragma unroll
  for (int j = 0; j < 2; ++j)
    bj[j] = bias[col0 + wx * 32 + j * 16 + l15];

#pragma unroll
  for (int i = 0; i < 4; ++i)
#pragma unroll
    for (int rr = 0; rr < 4; ++rr) {
      const size_t row = row0 + wy * 64 + i * 16 + quad * 4 + rr;
#pragma unroll
      for (int j = 0; j < 2; ++j) {
        const float v = (acc[i][j][rr] + bj[j]) * oscale;
        const int col = col0 + wx * 32 + j * 16 + l15;
        if (out_mode == 0) ((float*)Cout)[row * N + col] = v;
        else               ((u16*)Cout)[row * N + col] = f2bf(v);
      }
    }
}

// ---------------------------------------------------------------------------
// gemm64: 64x64-tile GEMM (kept for the N=64 K/V projections; fp32 A path).
// ---------------------------------------------------------------------------
#define GP 72
template <bool A_FP32>
static __device__ void gemm64(const float* __restrict__ Af32,
                              const u16* __restrict__ Abf,
                              const u16* __restrict__ Bt,
                              const float* __restrict__ bias,
                              void* __restrict__ Cout, int out_mode,
                              float oscale,
                              int row0, int col0, int N, int K, int ldT,
                              u16* As, u16* Bs) {
  const int tid  = threadIdx.x;
  const int lane = tid & 63;
  const int quad = lane >> 4, l15 = lane & 15;
  const int w = tid >> 6, wy = w >> 1, wx = w & 1;

  f32x4 acc[2][2];
#pragma unroll
  for (int i = 0; i < 2; ++i)
#pragma unroll
    for (int j = 0; j < 2; ++j) {
      acc[i][j][0] = 0.f; acc[i][j][1] = 0.f;
      acc[i][j][2] = 0.f; acc[i][j][3] = 0.f;
    }

  const int r = tid >> 2, c16 = (tid & 3) * 16;

  for (int k0 = 0; k0 < K; k0 += 64) {
    frag16 a0, a1;
    if (A_FP32) {
      const float* ap = Af32 + (size_t)(row0 + r) * K + k0 + c16;
      f4u x0, x1, x2, x3;
      x0.v = *(const float4*)(ap);
      x1.v = *(const float4*)(ap + 4);
      x2.v = *(const float4*)(ap + 8);
      x3.v = *(const float4*)(ap + 12);
      bf8u t0, t1;
      t0.w[0] = cvt_pk_bf16(x0.f[0], x0.f[1]);
      t0.w[1] = cvt_pk_bf16(x0.f[2], x0.f[3]);
      t0.w[2] = cvt_pk_bf16(x1.f[0], x1.f[1]);
      t0.w[3] = cvt_pk_bf16(x1.f[2], x1.f[3]);
      t1.w[0] = cvt_pk_bf16(x2.f[0], x2.f[1]);
      t1.w[1] = cvt_pk_bf16(x2.f[2], x2.f[3]);
      t1.w[2] = cvt_pk_bf16(x3.f[0], x3.f[1]);
      t1.w[3] = cvt_pk_bf16(x3.f[2], x3.f[3]);
      a0 = t0.v; a1 = t1.v;
    } else {
      const u16* ap = Abf + (size_t)(row0 + r) * K + k0 + c16;
      a0 = *(const frag16*)(ap);
      a1 = *(const frag16*)(ap + 8);
    }
    const u16* bp = Bt + (size_t)(col0 + r) * K + k0 + c16;
    const frag16 b0 = *(const frag16*)(bp);
    const frag16 b1 = *(const frag16*)(bp + 8);
    __syncthreads();
    *(frag16*)(&As[r * GP + c16])     = a0;
    *(frag16*)(&As[r * GP + c16 + 8]) = a1;
    *(frag16*)(&Bs[r * GP + c16])     = b0;
    *(frag16*)(&Bs[r * GP + c16 + 8]) = b1;
    __syncthreads();
#pragma unroll
    for (int ks = 0; ks < 2; ++ks) {
      frag16 af[2], bf[2];
#pragma unroll
      for (int i = 0; i < 2; ++i)
        af[i] = *(const frag16*)(&As[(wy * 32 + i * 16 + l15) * GP + ks * 32 + quad * 8]);
#pragma unroll
      for (int j = 0; j < 2; ++j)
        bf[j] = *(const frag16*)(&Bs[(wx * 32 + j * 16 + l15) * GP + ks * 32 + quad * 8]);
#pragma unroll
      for (int i = 0; i < 2; ++i)
#pragma unroll
        for (int j = 0; j < 2; ++j)
          acc[i][j] = __builtin_amdgcn_mfma_f32_16x16x32_bf16(af[i], bf[j], acc[i][j], 0, 0, 0);
    }
  }

  float bj[2];
#pragma unroll
  for (int j = 0; j < 2; ++j)
    bj[j] = bias[col0 + wx * 32 + j * 16 + l15];

#pragma unroll
  for (int i = 0; i < 2; ++i) {
#pragma unroll
    for (int rr = 0; rr < 4; ++rr) {
      const size_t row = row0 + wy * 32 + i * 16 + quad * 4 + rr;
#pragma unroll
      for (int j = 0; j < 2; ++j) {
        const float v = (acc[i][j][rr] + bj[j]) * oscale;
        const int col = col0 + wx * 32 + j * 16 + l15;
        if (out_mode == 0)      ((float*)Cout)[row * N + col] = v;
        else if (out_mode == 1) ((u16*)Cout)[row * N + col] = f2bf(v);
        else                    ((u16*)Cout)[(size_t)col * ldT + row] = f2bf(v);
      }
    }
  }
}

#define C2_SCALE 0.045084220027780106f   // log2(e)/32, folded into Q-proj

// blocks 0..511: Q-proj 128x64 tiles; 512..575: K-proj; 576..639: V-proj.
__global__ __launch_bounds__(256, 4)
void proj2(const float* __restrict__ key, const float* __restrict__ value,
           const u16* __restrict__ xq_bf,
           const u16* __restrict__ wq_t, const u16* __restrict__ wk_t,
           const u16* __restrict__ wv_t,
           const float* __restrict__ bq, const float* __restrict__ bk,
           const float* __restrict__ bv,
           u16* __restrict__ q_bf, u16* __restrict__ k_bf,
           u16* __restrict__ vt_bf, int M, int K) {
  __shared__ __align__(16) u16 smem[12288];   // 24 KB
  const int bid = blockIdx.x;
  if (bid < 512)
    gemm128n64(xq_bf, wq_t, bq, q_bf, 1, C2_SCALE,
               (bid >> 4) * 128, (bid & 15) * 64, 1024, K, smem, smem + 8192);
  else if (bid < 576)
    gemm64<true>(key, nullptr, wk_t, bk, k_bf, 1, 1.0f,
                 (bid - 512) * 64, 0, 64, K, 0, smem, smem + 64 * GP);
  else
    gemm64<true>(value, nullptr, wv_t, bv, vt_bf, 2, 1.0f,
                 (bid - 576) * 64, 0, 64, K, M, smem, smem + 64 * GP);
}

__global__ __launch_bounds__(256, 4)
void out_proj(const u16* __restrict__ ao, const u16* __restrict__ wo_t,
              const float* __restrict__ bo, float* __restrict__ out,
              int M, int K) {
  __shared__ __align__(16) u16 smem[12288];
  const int bid = blockIdx.x;
  gemm128n64(ao, wo_t, bo, out, 0, 1.0f,
             (bid >> 4) * 128, (bid & 15) * 64, 1024, K, smem, smem + 8192);
}

// ---------------------------------------------------------------------------
// Flash MQA attention (EXACT Round-10 body, verified at 57.2us):
// mfma_f32_32x32x16_bf16, S^T trick, 2-barrier T14 pipeline, P via LDS.
// grid (S/64, H, B), block 256 = 4 waves. Wave w: kh=w&1 key-half, qh=w>>1.
// ---------------------------------------------------------------------------
#define APITCH 72

__global__ __launch_bounds__(256, 4)
void mqa_flash_mfma(const u16* __restrict__ Qb,  // [B,S,1024] bf16 (pre-scaled by C2)
                    const u16* __restrict__ Kb,  // [B,S,64]   bf16
                    const u16* __restrict__ Vt,  // [64][B*S]  bf16 (transposed)
                    u16* __restrict__ O) {       // [B,S,1024] bf16
  const int S = 2048, HID = 1024, D = 64, BS = 4096;
  __shared__ u16 Ks[64 * APITCH];   // K[key][d]
  __shared__ u16 Vs[64 * APITCH];   // V^T[d][key]
  __shared__ u16 Ps[64 * APITCH];   // P[q][key]
  __shared__ float red[2][64];      // per-key-half l partials

  const int tid  = threadIdx.x;
  const int lane = tid & 63;
  const int w    = tid >> 6;
  const int l31  = lane & 31;
  const int hh   = lane >> 5;        // lane half (0/1)
  const int kh   = w & 1;            // key-half for scores / d-half for PV
  const int qh   = w >> 1;           // q-half
  const int qb = blockIdx.x, h = blockIdx.y, b = blockIdx.z;

  const int sr = tid >> 3;           // 0..31 staging row
  const int sc = (tid & 7) * 8;      // staging col (x8 u16)

  const u16* qrow = Qb + (size_t)(b * S + qb * 64 + qh * 32 + l31) * HID + h * D;
  frag16 qf[4];
#pragma unroll
  for (int ks = 0; ks < 4; ++ks)
    qf[ks] = *(const frag16*)(qrow + ks * 16 + hh * 8);

  f32x16 zero16;
#pragma unroll
  for (int r = 0; r < 16; ++r) zero16[r] = 0.f;

  f32x16 o_acc;
#pragma unroll
  for (int r = 0; r < 16; ++r) o_acc[r] = 0.f;
  float l_lane = 0.f;

  const u16* kbase = Kb + (size_t)(b * S) * D;   // K[key][d], key rel. to batch
  const u16* vbase = Vt + (size_t)(b * S);       // Vt[d][key]

  // ---- prologue: chunk 0 -> regs -> LDS ----
  frag16 pk0 = *(const frag16*)(kbase + (size_t)sr * D + sc);
  frag16 pk1 = *(const frag16*)(kbase + (size_t)(sr + 32) * D + sc);
  frag16 pv0 = *(const frag16*)(vbase + (size_t)sr * BS + sc);
  frag16 pv1 = *(const frag16*)(vbase + (size_t)(sr + 32) * BS + sc);
  *(frag16*)(&Ks[sr * APITCH + sc])        = pk0;
  *(frag16*)(&Ks[(sr + 32) * APITCH + sc]) = pk1;
  *(frag16*)(&Vs[sr * APITCH + sc])        = pv0;
  *(frag16*)(&Vs[(sr + 32) * APITCH + sc]) = pv1;
  __syncthreads();

  for (int kc = 0; kc < S; kc += 64) {
    const int nc = (kc + 64 < S) ? kc + 64 : kc;
    pk0 = *(const frag16*)(kbase + (size_t)(nc + sr) * D + sc);
    pk1 = *(const frag16*)(kbase + (size_t)(nc + sr + 32) * D + sc);
    pv0 = *(const frag16*)(vbase + (size_t)sr * BS + nc + sc);
    pv1 = *(const frag16*)(vbase + (size_t)(sr + 32) * BS + nc + sc);

    frag16 vf[4];
#pragma unroll
    for (int ks = 0; ks < 4; ++ks)
      vf[ks] = *(const frag16*)(&Vs[(kh * 32 + l31) * APITCH + ks * 16 + hh * 8]);

    f32x16 sa;
#pragma unroll
    for (int ks = 0; ks < 4; ++ks) {
      const frag16 kf = *(const frag16*)(&Ks[(kh * 32 + l31) * APITCH + ks * 16 + hh * 8]);
      sa = __builtin_amdgcn_mfma_f32_32x32x16_bf16(kf, qf[ks], ks ? sa : zero16, 0, 0, 0);
    }

    const int qrow_l = qh * 32 + l31;
    u16* prow = &Ps[qrow_l * APITCH + kh * 32];
#pragma unroll
    for (int g = 0; g < 4; ++g) {
      const float p0 = __builtin_amdgcn_exp2f(sa[g * 4 + 0]);
      const float p1 = __builtin_amdgcn_exp2f(sa[g * 4 + 1]);
      const float p2 = __builtin_amdgcn_exp2f(sa[g * 4 + 2]);
      const float p3 = __builtin_amdgcn_exp2f(sa[g * 4 + 3]);
      l_lane += (p0 + p1) + (p2 + p3);
      uint2 pk;
      pk.x = cvt_pk_bf16(p0, p1);
      pk.y = cvt_pk_bf16(p2, p3);
      *(uint2*)(&prow[g * 8 + hh * 4]) = pk;
    }
    __syncthreads();  // sync1: Ps ready; all Ks/Vs reads of this chunk done

#pragma unroll
    for (int ks = 0; ks < 4; ++ks) {
      const frag16 pf = *(const frag16*)(&Ps[(qh * 32 + l31) * APITCH + ks * 16 + hh * 8]);
      o_acc = __builtin_amdgcn_mfma_f32_32x32x16_bf16(pf, vf[ks], o_acc, 0, 0, 0);
    }

    *(frag16*)(&Ks[sr * APITCH + sc])        = pk0;
    *(frag16*)(&Ks[(sr + 32) * APITCH + sc]) = pk1;
    *(frag16*)(&Vs[sr * APITCH + sc])        = pv0;
    *(frag16*)(&Vs[(sr + 32) * APITCH + sc]) = pv1;
    __syncthreads();  // sync2: KV ready for t+1; Ps write-safe for t+1
  }

  l_lane += __shfl_xor(l_lane, 32);
  __syncthreads();
  if (lane < 32) red[kh][qh * 32 + l31] = l_lane;
  __syncthreads();

#pragma unroll
  for (int r = 0; r < 16; ++r) {
    const int q_local = qh * 32 + (r & 3) + 8 * (r >> 2) + 4 * hh;
    const float li = 1.f / (red[0][q_local] + red[1][q_local]);
    u16* orow = O + (size_t)(b * S + qb * 64 + q_local) * HID + h * D;
    orow[kh * 32 + l31] = f2bf(o_acc[r] * li);
  }
}

extern "C" void kernel_launch(void* const* d_in, const int* in_sizes, int n_in,
                              void* d_out, int out_size, void* d_ws, size_t ws_size,
                              hipStream_t stream) {
  const float* query = (const float*)d_in[0];
  const float* key   = (const float*)d_in[1];
  const float* value = (const float*)d_in[2];
  const float* Wq    = (const float*)d_in[3];
  const float* bq    = (const float*)d_in[4];
  const float* Wk    = (const float*)d_in[5];
  const float* bk    = (const float*)d_in[6];
  const float* Wv    = (const float*)d_in[7];
  const float* bv    = (const float*)d_in[8];
  const float* Wo    = (const float*)d_in[9];
  const float* bo    = (const float*)d_in[10];
  float* out = (float*)d_out;

  const int B = 2, S = 2048, IN = 1024, HID = 1024, H = 16, D = 64;
  const int M = B * S;  // 4096
  const size_t MB = 1024 * 1024;

  char* ws = (char*)d_ws;
  u16* q_bf  = (u16*)ws;                           // [0, 8MB)
  u16* ao_bf = (u16*)(ws + 8 * MB);                // [8, 16MB)  (mqa -> out_proj)
  u16* xq_bf = ao_bf;                              // same slot (prep -> proj2)
  u16* k_bf  = (u16*)(ws + 16 * MB);               // 0.5 MB
  u16* vt_bf = (u16*)(ws + 16 * MB + 512 * 1024);  // 0.5 MB
  u16* wq_t  = (u16*)(ws + 17 * MB);               // 2 MB [1024][1024]
  u16* wo_t  = (u16*)(ws + 19 * MB);               // 2 MB [1024][1024]
  u16* wk_t  = (u16*)(ws + 21 * MB);               // 128 KB [64][1024]
  u16* wv_t  = (u16*)(ws + 21 * MB + 128 * 1024);  // 128 KB [64][1024]

  dim3 blk(256);
  prep_w<<<dim3(1568), blk, 0, stream>>>(Wq, Wo, Wk, Wv, query,
                                         wq_t, wo_t, wk_t, wv_t, xq_bf);
  proj2<<<dim3(640), blk, 0, stream>>>(key, value, xq_bf, wq_t, wk_t, wv_t,
                                       bq, bk, bv, q_bf, k_bf, vt_bf, M, IN);
  mqa_flash_mfma<<<dim3(S / 64, H, B), blk, 0, stream>>>(q_bf, k_bf, vt_bf, ao_bf);
  out_proj<<<dim3(512), blk, 0, stream>>>(ao_bf, wo_t, bo, out, M, HID);
}